// Round 1
// baseline (1617.812 us; speedup 1.0000x reference)
//
#include <hip/hip_runtime.h>
#include <cstdint>
#include <cstddef>

// RNNDec GRU rollout: N=4096 samples, H=512 hidden, T=12 steps, out 2-dim.
// Strategy: precompute gi_base (zx part of input gates) once; per step only the
// recurrent GEMM gh = h @ W_hh^T (4096x1536x512) via bf16 MFMA with hi+lo split
// of h for precision. h state kept in fp32 (ping-pong). Gate math fp32.

typedef __attribute__((ext_vector_type(8))) __bf16 bf16x8;
typedef __attribute__((ext_vector_type(4))) float floatx4;

__device__ __forceinline__ float sigm_f(float v) {
    return 1.0f / (1.0f + __expf(-v));
}
__device__ __forceinline__ float tanh_f(float v) {
    return 2.0f / (1.0f + __expf(-2.0f * v)) - 1.0f;
}

// ---------------- K0: casts + a0 ----------------
__global__ __launch_bounds__(256) void k0_prep(
    const float* __restrict__ z, const float* __restrict__ x,
    const float* __restrict__ x0, const float* __restrict__ W_ia,
    const float* __restrict__ b_ia, const float* __restrict__ W_ih,
    const float* __restrict__ W_hh, const float* __restrict__ W_h0,
    __bf16* __restrict__ zx_hi, __bf16* __restrict__ zx_lo,
    __bf16* __restrict__ wh0_b, __bf16* __restrict__ wih_b,
    __bf16* __restrict__ whh_b, float* __restrict__ xbuf)
{
    const int ZX  = 4096 * 256;   // zx elements
    const int WH0 = 512 * 256;
    const int WIH = 1536 * 256;
    const int WHH = 1536 * 512;
    const int A0  = 4096 * 2;
    const int total = ZX + WH0 + WIH + WHH + A0;
    for (int idx = blockIdx.x * 256 + threadIdx.x; idx < total; idx += gridDim.x * 256) {
        if (idx < ZX) {
            int i = idx >> 8, k = idx & 255;
            float v = (k < 128) ? z[i * 128 + k] : x[i * 128 + (k - 128)];
            __bf16 hi = (__bf16)v;
            zx_hi[idx] = hi;
            zx_lo[idx] = (__bf16)(v - (float)hi);
        } else if (idx < ZX + WH0) {
            int j = idx - ZX;
            wh0_b[j] = (__bf16)W_h0[j];
        } else if (idx < ZX + WH0 + WIH) {
            int j = idx - ZX - WH0;
            int r = j >> 8, c = j & 255;
            wih_b[j] = (__bf16)W_ih[r * 258 + c];   // pack first 256 cols, stride 256
        } else if (idx < ZX + WH0 + WIH + WHH) {
            int j = idx - ZX - WH0 - WIH;
            whh_b[j] = (__bf16)W_hh[j];
        } else {
            int j = idx - ZX - WH0 - WIH - WHH;
            int i = j >> 1, d = j & 1;
            float s = b_ia[d];
            #pragma unroll
            for (int k = 0; k < 4; k++) s += x0[i * 4 + k] * W_ia[d * 4 + k];
            xbuf[j] = s;   // a0 = initial action
        }
    }
}

// ---------------- K1: fused GEMM for h0 (N cols 0..511) and gi_base (cols 512..2047) ----------------
// C[4096 x 2048] = zx(hi+lo) @ Bcat^T, K=256. MFMA 16x16x32 bf16.
__global__ __launch_bounds__(256) void k1_precompute(
    const __bf16* __restrict__ zx_hi, const __bf16* __restrict__ zx_lo,
    const __bf16* __restrict__ wh0_b, const __bf16* __restrict__ wih_b,
    const float* __restrict__ b_h0, const float* __restrict__ b_ih,
    float* __restrict__ hf0, __bf16* __restrict__ hb0_hi, __bf16* __restrict__ hb0_lo,
    float* __restrict__ gi_base)
{
    int w = threadIdx.x >> 6, lane = threadIdx.x & 63;
    int quad = lane >> 4, l15 = lane & 15;
    int m_sub = w >> 1, n_sub = w & 1;
    int mrow = blockIdx.x * 32 + m_sub * 16 + l15;
    int ncol = blockIdx.y * 32 + n_sub * 16 + l15;
    const bf16x8* ah = (const bf16x8*)(zx_hi + (size_t)mrow * 256);
    const bf16x8* al = (const bf16x8*)(zx_lo + (size_t)mrow * 256);
    const __bf16* brow = (ncol < 512) ? (wh0_b + (size_t)ncol * 256)
                                      : (wih_b + (size_t)(ncol - 512) * 256);
    const bf16x8* bv = (const bf16x8*)brow;
    floatx4 acc = {0.f, 0.f, 0.f, 0.f};
    #pragma unroll 4
    for (int kk = 0; kk < 8; kk++) {
        int vi = quad + kk * 4;
        bf16x8 b = bv[vi];
        acc = __builtin_amdgcn_mfma_f32_16x16x32_bf16(ah[vi], b, acc, 0, 0, 0);
        acc = __builtin_amdgcn_mfma_f32_16x16x32_bf16(al[vi], b, acc, 0, 0, 0);
    }
    #pragma unroll
    for (int p = 0; p < 4; p++) {
        int i = blockIdx.x * 32 + m_sub * 16 + quad * 4 + p;  // C/D row = quad*4+p
        float v = acc[p];
        if (ncol < 512) {
            float h = v + b_h0[ncol];
            hf0[(size_t)i * 512 + ncol] = h;
            __bf16 hi = (__bf16)h;
            hb0_hi[(size_t)i * 512 + ncol] = hi;
            hb0_lo[(size_t)i * 512 + ncol] = (__bf16)(h - (float)hi);
        } else {
            int c = ncol - 512;
            gi_base[(size_t)i * 1536 + c] = v + b_ih[c];
        }
    }
}

// ---------------- K2: one GRU step ----------------
// Block tile: 32 samples x 32 hidden units x 3 gates. grid (128, 16), 256 thr.
// Also computes out_{t-1} = W_out @ h_t + b_out at kernel start (feeds x_t and d_out).
__global__ __launch_bounds__(256) void k2_step(
    int t,
    const float* __restrict__ hf_in, const __bf16* __restrict__ hb_hi_in,
    const __bf16* __restrict__ hb_lo_in,
    float* __restrict__ hf_out, __bf16* __restrict__ hb_hi_out,
    __bf16* __restrict__ hb_lo_out,
    const __bf16* __restrict__ whh_b, const float* __restrict__ gi_base,
    const float* __restrict__ W_ih, const float* __restrict__ b_hh,
    const float* __restrict__ W_out, const float* __restrict__ b_out,
    const float* __restrict__ xbuf, float* __restrict__ dout)
{
    __shared__ float xs[32][2];
    __shared__ float xpart[32][8][2];
    int tid = threadIdx.x;
    int bx = blockIdx.x, by = blockIdx.y;

    if (t == 0) {
        if (tid < 64) {
            int s = tid >> 1, d = tid & 1;
            xs[s][d] = xbuf[(bx * 32 + s) * 2 + d];
        }
    } else {
        // out_{t-1} = W_out @ h_t + b_out for this block's 32 samples
        int s = tid >> 3, part = tid & 7;
        const __bf16* hrow = hb_hi_in + (size_t)(bx * 32 + s) * 512 + part * 64;
        const float* w0 = W_out + part * 64;
        const float* w1 = W_out + 512 + part * 64;
        float p0 = 0.f, p1 = 0.f;
        #pragma unroll 8
        for (int k = 0; k < 64; k++) {
            float hv = (float)hrow[k];
            p0 += hv * w0[k];
            p1 += hv * w1[k];
        }
        xpart[s][part][0] = p0;
        xpart[s][part][1] = p1;
        __syncthreads();
        if (tid < 64) {
            int s2 = tid >> 1, d = tid & 1;
            float v = b_out[d];
            #pragma unroll
            for (int q = 0; q < 8; q++) v += xpart[s2][q][d];
            xs[s2][d] = v;
            if (by == 0) dout[((size_t)(bx * 32 + s2) * 12 + (t - 1)) * 2 + d] = v;
        }
    }
    __syncthreads();

    // --- recurrent GEMM: gh = h(hi+lo) @ W_hh^T for 3 gates ---
    int w = tid >> 6, lane = tid & 63;
    int quad = lane >> 4, l15 = lane & 15;
    int m_sub = w >> 1, n_sub = w & 1;
    int mrow = bx * 32 + m_sub * 16 + l15;                // A-frag row (m = l15)
    int jcol = by * 32 + n_sub * 16 + l15;                // B-frag col (n = l15), j in [0,512)
    const bf16x8* ah = (const bf16x8*)(hb_hi_in + (size_t)mrow * 512);
    const bf16x8* al = (const bf16x8*)(hb_lo_in + (size_t)mrow * 512);
    const bf16x8* br = (const bf16x8*)(whh_b + (size_t)jcol * 512);
    const bf16x8* bz = (const bf16x8*)(whh_b + (size_t)(512 + jcol) * 512);
    const bf16x8* bn = (const bf16x8*)(whh_b + (size_t)(1024 + jcol) * 512);
    floatx4 accr = {0.f, 0.f, 0.f, 0.f};
    floatx4 accz = {0.f, 0.f, 0.f, 0.f};
    floatx4 accn = {0.f, 0.f, 0.f, 0.f};
    #pragma unroll 4
    for (int kk = 0; kk < 16; kk++) {
        int vi = quad + kk * 4;
        bf16x8 a_hi = ah[vi];
        bf16x8 a_lo = al[vi];
        bf16x8 vbr = br[vi], vbz = bz[vi], vbn = bn[vi];
        accr = __builtin_amdgcn_mfma_f32_16x16x32_bf16(a_hi, vbr, accr, 0, 0, 0);
        accz = __builtin_amdgcn_mfma_f32_16x16x32_bf16(a_hi, vbz, accz, 0, 0, 0);
        accn = __builtin_amdgcn_mfma_f32_16x16x32_bf16(a_hi, vbn, accn, 0, 0, 0);
        accr = __builtin_amdgcn_mfma_f32_16x16x32_bf16(a_lo, vbr, accr, 0, 0, 0);
        accz = __builtin_amdgcn_mfma_f32_16x16x32_bf16(a_lo, vbz, accz, 0, 0, 0);
        accn = __builtin_amdgcn_mfma_f32_16x16x32_bf16(a_lo, vbn, accn, 0, 0, 0);
    }

    // --- epilogue: gates + state update (all three gates live in same lane/reg) ---
    int cr = jcol, cz = 512 + jcol, cn = 1024 + jcol;
    float wxr0 = W_ih[cr * 258 + 256], wxr1 = W_ih[cr * 258 + 257];
    float wxz0 = W_ih[cz * 258 + 256], wxz1 = W_ih[cz * 258 + 257];
    float wxn0 = W_ih[cn * 258 + 256], wxn1 = W_ih[cn * 258 + 257];
    float bhr = b_hh[cr], bhz = b_hh[cz], bhn = b_hh[cn];
    #pragma unroll
    for (int p = 0; p < 4; p++) {
        int li = m_sub * 16 + quad * 4 + p;   // C/D row within tile
        int i = bx * 32 + li;
        float x0v = xs[li][0], x1v = xs[li][1];
        const float* gib = gi_base + (size_t)i * 1536;
        float gir = gib[cr] + wxr0 * x0v + wxr1 * x1v;
        float giz = gib[cz] + wxz0 * x0v + wxz1 * x1v;
        float gin = gib[cn] + wxn0 * x0v + wxn1 * x1v;
        float r = sigm_f(gir + accr[p] + bhr);
        float u = sigm_f(giz + accz[p] + bhz);
        float nn = tanh_f(gin + r * (accn[p] + bhn));
        float hold = hf_in[(size_t)i * 512 + jcol];
        float hn = (1.f - u) * nn + u * hold;
        hf_out[(size_t)i * 512 + jcol] = hn;
        __bf16 hi = (__bf16)hn;
        hb_hi_out[(size_t)i * 512 + jcol] = hi;
        hb_lo_out[(size_t)i * 512 + jcol] = (__bf16)(hn - (float)hi);
    }
}

// ---------------- K3: final output out_11 = W_out @ h_12 + b_out ----------------
__global__ __launch_bounds__(256) void k3_final(
    const __bf16* __restrict__ hb_hi, const float* __restrict__ W_out,
    const float* __restrict__ b_out, float* __restrict__ dout)
{
    __shared__ float xpart[32][8][2];
    int tid = threadIdx.x, bx = blockIdx.x;
    int s = tid >> 3, part = tid & 7;
    const __bf16* hrow = hb_hi + (size_t)(bx * 32 + s) * 512 + part * 64;
    const float* w0 = W_out + part * 64;
    const float* w1 = W_out + 512 + part * 64;
    float p0 = 0.f, p1 = 0.f;
    #pragma unroll 8
    for (int k = 0; k < 64; k++) {
        float hv = (float)hrow[k];
        p0 += hv * w0[k];
        p1 += hv * w1[k];
    }
    xpart[s][part][0] = p0;
    xpart[s][part][1] = p1;
    __syncthreads();
    if (tid < 64) {
        int s2 = tid >> 1, d = tid & 1;
        float v = b_out[d];
        #pragma unroll
        for (int q = 0; q < 8; q++) v += xpart[s2][q][d];
        dout[((size_t)(bx * 32 + s2) * 12 + 11) * 2 + d] = v;
    }
}

extern "C" void kernel_launch(void* const* d_in, const int* in_sizes, int n_in,
                              void* d_out, int out_size, void* d_ws, size_t ws_size,
                              hipStream_t stream)
{
    const float* z     = (const float*)d_in[0];
    const float* x     = (const float*)d_in[1];
    const float* x0    = (const float*)d_in[2];
    const float* W_ia  = (const float*)d_in[3];
    const float* b_ia  = (const float*)d_in[4];
    const float* W_h0  = (const float*)d_in[5];
    const float* b_h0  = (const float*)d_in[6];
    const float* W_ih  = (const float*)d_in[7];
    const float* b_ih  = (const float*)d_in[8];
    const float* W_hh  = (const float*)d_in[9];
    const float* b_hh  = (const float*)d_in[10];
    const float* W_out = (const float*)d_in[11];
    const float* b_out = (const float*)d_in[12];
    float* dout = (float*)d_out;

    char* ws = (char*)d_ws;
    size_t off = 0;
    float*  hf[2];  __bf16* hhi[2];  __bf16* hlo[2];
    hf[0]  = (float*)(ws + off);  off += (size_t)4096 * 512 * 4;
    hf[1]  = (float*)(ws + off);  off += (size_t)4096 * 512 * 4;
    hhi[0] = (__bf16*)(ws + off); off += (size_t)4096 * 512 * 2;
    hhi[1] = (__bf16*)(ws + off); off += (size_t)4096 * 512 * 2;
    hlo[0] = (__bf16*)(ws + off); off += (size_t)4096 * 512 * 2;
    hlo[1] = (__bf16*)(ws + off); off += (size_t)4096 * 512 * 2;
    float* gi_base = (float*)(ws + off); off += (size_t)4096 * 1536 * 4;
    __bf16* zx_hi = (__bf16*)(ws + off); off += (size_t)4096 * 256 * 2;
    __bf16* zx_lo = (__bf16*)(ws + off); off += (size_t)4096 * 256 * 2;
    __bf16* wh0_b = (__bf16*)(ws + off); off += (size_t)512 * 256 * 2;
    __bf16* wih_b = (__bf16*)(ws + off); off += (size_t)1536 * 256 * 2;
    __bf16* whh_b = (__bf16*)(ws + off); off += (size_t)1536 * 512 * 2;
    float* xbuf = (float*)(ws + off); off += (size_t)4096 * 2 * 4;

    k0_prep<<<1024, 256, 0, stream>>>(z, x, x0, W_ia, b_ia, W_ih, W_hh, W_h0,
                                      zx_hi, zx_lo, wh0_b, wih_b, whh_b, xbuf);
    k1_precompute<<<dim3(128, 64), 256, 0, stream>>>(zx_hi, zx_lo, wh0_b, wih_b,
                                                     b_h0, b_ih, hf[0], hhi[0], hlo[0], gi_base);
    for (int t = 0; t < 12; t++) {
        int ib = t & 1, ob = (t + 1) & 1;
        k2_step<<<dim3(128, 16), 256, 0, stream>>>(t, hf[ib], hhi[ib], hlo[ib],
                                                   hf[ob], hhi[ob], hlo[ob],
                                                   whh_b, gi_base, W_ih, b_hh,
                                                   W_out, b_out, xbuf, dout);
    }
    k3_final<<<128, 256, 0, stream>>>(hhi[0], W_out, b_out, dout);
}

// Round 2
// 360.765 us; speedup vs baseline: 4.4844x; 4.4844x over previous
//
#include <hip/hip_runtime.h>
#include <cstdint>
#include <cstddef>

// RNNDec GRU rollout: N=4096, H=512, T=12. R2: MFMA GEMM with global_load_lds
// staging, 32x32x16 bf16 tiles, hi+lo bf16 split of activations for precision.
// Per step: gh = h@W_hh^T fused with gates; x_t via partial-slot reduction.

typedef __attribute__((ext_vector_type(8))) __bf16 bf16x8;
typedef __attribute__((ext_vector_type(16))) float floatx16;

__device__ __forceinline__ float sigm_f(float v) {
    return 1.0f / (1.0f + __expf(-v));
}
__device__ __forceinline__ float tanh_f(float v) {
    return 2.0f / (1.0f + __expf(-2.0f * v)) - 1.0f;
}

__device__ __forceinline__ void async16(void* lds, const void* g) {
    __builtin_amdgcn_global_load_lds(
        (const __attribute__((address_space(1))) void*)g,
        (__attribute__((address_space(3))) void*)lds, 16, 0, 0);
}

// ---------------- K0: casts + packing + a0 ----------------
__global__ __launch_bounds__(256) void k0_prep(
    const float* __restrict__ z, const float* __restrict__ x,
    const float* __restrict__ x0, const float* __restrict__ W_ia,
    const float* __restrict__ b_ia, const float* __restrict__ W_ih,
    const float* __restrict__ W_hh, const float* __restrict__ W_h0,
    const float* __restrict__ W_out, const float* __restrict__ b_hh,
    __bf16* __restrict__ zx_hi, __bf16* __restrict__ zx_lo,
    __bf16* __restrict__ wcat, __bf16* __restrict__ whh_b,
    float* __restrict__ pk, float* __restrict__ xbuf)
{
    const int ZX = 4096 * 256;
    const int WC = 2048 * 256;
    const int WH = 1536 * 512;
    const int PKN = 512;
    const int XB = 4096 * 2;
    const int total = ZX + WC + WH + PKN + XB;
    for (int idx = blockIdx.x * 256 + threadIdx.x; idx < total; idx += gridDim.x * 256) {
        if (idx < ZX) {
            int i = idx >> 8, k = idx & 255;
            float v = (k < 128) ? z[i * 128 + k] : x[i * 128 + (k - 128)];
            __bf16 h = (__bf16)v;
            zx_hi[idx] = h;
            zx_lo[idx] = (__bf16)(v - (float)h);
        } else if (idx < ZX + WC) {
            int j = idx - ZX;
            int n = j >> 8, k = j & 255;
            float v = (n < 512) ? W_h0[n * 256 + k] : W_ih[(n - 512) * 258 + k];
            wcat[j] = (__bf16)v;
        } else if (idx < ZX + WC + WH) {
            int j = idx - ZX - WC;
            whh_b[j] = (__bf16)W_hh[j];
        } else if (idx < ZX + WC + WH + PKN) {
            int jc = idx - ZX - WC - WH;
            float* o = pk + jc * 12;
            o[0] = W_ih[jc * 258 + 256];          o[1] = W_ih[jc * 258 + 257];
            o[2] = W_ih[(512 + jc) * 258 + 256];  o[3] = W_ih[(512 + jc) * 258 + 257];
            o[4] = W_ih[(1024 + jc) * 258 + 256]; o[5] = W_ih[(1024 + jc) * 258 + 257];
            o[6] = b_hh[jc]; o[7] = b_hh[512 + jc]; o[8] = b_hh[1024 + jc];
            o[9] = W_out[jc]; o[10] = W_out[512 + jc]; o[11] = 0.f;
        } else {
            int j = idx - ZX - WC - WH - PKN;
            int i = j >> 1, d = j & 1;
            float s = b_ia[d];
            #pragma unroll
            for (int k2 = 0; k2 < 4; k2++) s += x0[i * 4 + k2] * W_ia[d * 4 + k2];
            xbuf[j] = s;
        }
    }
}

// ---------------- K1: h0 (cols 0..511) + gi_base (cols 512..2047) ----------------
// C[4096 x 2048] = zx(hi+lo) @ wcat^T, K=256. Tile 128m x 64n, BK=64, 4 chunks.
__global__ __launch_bounds__(256) void k1_precompute(
    const __bf16* __restrict__ zx_hi, const __bf16* __restrict__ zx_lo,
    const __bf16* __restrict__ wcat,
    const float* __restrict__ b_h0, const float* __restrict__ b_ih,
    __bf16* __restrict__ hhi0, __bf16* __restrict__ hlo0,
    float* __restrict__ gi2)
{
    __shared__ __align__(16) char smem[40960];
    const uint32_t BOFF = 0, AHI = 8192, ALO = 24576;
    int tid = threadIdx.x;
    int w = tid >> 6, lane = tid & 63;
    int half = lane >> 5, l31 = lane & 31;
    int rsub = lane >> 3, csub = lane & 7;
    int Mb = blockIdx.x * 128, Nb = blockIdx.y * 64;

    const __bf16* gsrc[10];
    uint32_t ldso[10];
    #pragma unroll
    for (int j = 0; j < 10; j++) {
        int L = w + 4 * j;
        if (L < 16) {
            int r = L * 8 + rsub;
            gsrc[j] = zx_hi + (size_t)(Mb + r) * 256 + ((csub ^ (r & 7)) << 3);
            ldso[j] = AHI + ((uint32_t)(L * 8) << 7);
        } else if (L < 32) {
            int r = (L - 16) * 8 + rsub;
            gsrc[j] = zx_lo + (size_t)(Mb + r) * 256 + ((csub ^ (r & 7)) << 3);
            ldso[j] = ALO + ((uint32_t)((L - 16) * 8) << 7);
        } else {
            int rb = (L - 32) * 8 + rsub;
            gsrc[j] = wcat + (size_t)(Nb + rb) * 256 + ((csub ^ (rb & 7)) << 3);
            ldso[j] = BOFF + ((uint32_t)((L - 32) * 8) << 7);
        }
    }

    floatx16 acc0 = {0,0,0,0,0,0,0,0,0,0,0,0,0,0,0,0};
    floatx16 acc1 = {0,0,0,0,0,0,0,0,0,0,0,0,0,0,0,0};

    for (int kc = 0; kc < 4; kc++) {
        #pragma unroll
        for (int j = 0; j < 10; j++) async16(smem + ldso[j], gsrc[j] + kc * 64);
        __syncthreads();
        #pragma unroll
        for (int ks = 0; ks < 4; ks++) {
            int ch = ks * 2 + half;
            int ar = (w << 5) | l31;
            uint32_t aoff = ((uint32_t)ar << 7) | ((uint32_t)(ch ^ (ar & 7)) << 4);
            bf16x8 ahi = *(const bf16x8*)(smem + AHI + aoff);
            bf16x8 alo = *(const bf16x8*)(smem + ALO + aoff);
            uint32_t sw = (uint32_t)(ch ^ (l31 & 7)) << 4;
            bf16x8 b0 = *(const bf16x8*)(smem + BOFF + ((uint32_t)l31 << 7) + sw);
            bf16x8 b1 = *(const bf16x8*)(smem + BOFF + ((uint32_t)(32 + l31) << 7) + sw);
            acc0 = __builtin_amdgcn_mfma_f32_32x32x16_bf16(ahi, b0, acc0, 0, 0, 0);
            acc0 = __builtin_amdgcn_mfma_f32_32x32x16_bf16(alo, b0, acc0, 0, 0, 0);
            acc1 = __builtin_amdgcn_mfma_f32_32x32x16_bf16(ahi, b1, acc1, 0, 0, 0);
            acc1 = __builtin_amdgcn_mfma_f32_32x32x16_bf16(alo, b1, acc1, 0, 0, 0);
        }
        __syncthreads();
    }

    #pragma unroll
    for (int nt = 0; nt < 2; nt++) {
        int ncol = Nb + nt * 32 + l31;
        floatx16 acc = nt ? acc1 : acc0;
        #pragma unroll
        for (int reg = 0; reg < 16; reg++) {
            int row = (reg & 3) + 8 * (reg >> 2) + 4 * half;
            size_t i = (size_t)Mb + (w << 5) + row;
            float v = acc[reg];
            if (ncol < 512) {
                float h = v + b_h0[ncol];
                __bf16 hb = (__bf16)h;
                hhi0[i * 512 + ncol] = hb;
                hlo0[i * 512 + ncol] = (__bf16)(h - (float)hb);
            } else {
                int c = ncol - 512;
                int g = c >> 9, jc = c & 511;
                gi2[((size_t)i * 512 + jc) * 3 + g] = v + b_ih[c];
            }
        }
    }
}

// ---------------- K2: one GRU step ----------------
// Tile 128m x (32 jc x 3 gates). grid (32,16), 256 thr = 4 waves.
// Wave = 32m x 96n: accs accR/accZ/accN (32x32 each) -> all 3 gates same lane/reg.
__global__ __launch_bounds__(256) void k2_step(
    int t,
    const __bf16* __restrict__ hhi_in, const __bf16* __restrict__ hlo_in,
    __bf16* __restrict__ hhi_out, __bf16* __restrict__ hlo_out,
    const __bf16* __restrict__ whh_b, const float* __restrict__ gi2,
    const float* __restrict__ pk, const float* __restrict__ xbuf,
    float* __restrict__ partial, float* __restrict__ dout,
    const float* __restrict__ b_out)
{
    __shared__ __align__(16) char smem[46080];
    const uint32_t BOFF = 0, AHI = 12288, ALO = 28672, XSOFF = 45056;
    int tid = threadIdx.x;
    int bx = blockIdx.x, by = blockIdx.y;
    int Mbase = bx * 128, Jbase = by * 32;
    int w = tid >> 6, lane = tid & 63;
    int half = lane >> 5, l31 = lane & 31;
    int rsub = lane >> 3, csub = lane & 7;
    float* xs = (float*)(smem + XSOFF);  // [128][2]

    // prologue: x_t for this block's 128 samples (and write out_{t-1})
    {
        int i = tid >> 1, d = tid & 1;
        float v;
        if (t == 0) {
            v = xbuf[(size_t)(Mbase + i) * 2 + d];
        } else {
            const float4* p = (const float4*)(partial + ((size_t)(Mbase + i) * 2 + d) * 16);
            float4 a = p[0], b = p[1], c = p[2], e = p[3];
            v = b_out[d] + a.x + a.y + a.z + a.w + b.x + b.y + b.z + b.w
                         + c.x + c.y + c.z + c.w + e.x + e.y + e.z + e.w;
            if (by == 0) dout[((size_t)(Mbase + i) * 12 + (t - 1)) * 2 + d] = v;
        }
        xs[i * 2 + d] = v;
    }

    // staging pointers (chunk 0); advance by 64 bf16 per chunk
    const __bf16* gsrc[11];
    uint32_t ldso[11];
    #pragma unroll
    for (int j = 0; j < 11; j++) {
        int L = w + 4 * j;
        if (L < 16) {
            int r = L * 8 + rsub;
            gsrc[j] = hhi_in + (size_t)(Mbase + r) * 512 + ((csub ^ (r & 7)) << 3);
            ldso[j] = AHI + ((uint32_t)(L * 8) << 7);
        } else if (L < 32) {
            int r = (L - 16) * 8 + rsub;
            gsrc[j] = hlo_in + (size_t)(Mbase + r) * 512 + ((csub ^ (r & 7)) << 3);
            ldso[j] = ALO + ((uint32_t)((L - 16) * 8) << 7);
        } else {
            int rb = (L - 32) * 8 + rsub;   // 0..95: rb = g*32 + jin
            int g = rb >> 5, jin = rb & 31;
            gsrc[j] = whh_b + (size_t)(g * 512 + Jbase + jin) * 512 + ((csub ^ (rb & 7)) << 3);
            ldso[j] = BOFF + ((uint32_t)((L - 32) * 8) << 7);
        }
    }

    floatx16 accR = {0,0,0,0,0,0,0,0,0,0,0,0,0,0,0,0};
    floatx16 accZ = {0,0,0,0,0,0,0,0,0,0,0,0,0,0,0,0};
    floatx16 accN = {0,0,0,0,0,0,0,0,0,0,0,0,0,0,0,0};

    for (int kc = 0; kc < 8; kc++) {
        #pragma unroll
        for (int j = 0; j < 11; j++) async16(smem + ldso[j], gsrc[j] + kc * 64);
        __syncthreads();
        #pragma unroll
        for (int ks = 0; ks < 4; ks++) {
            int ch = ks * 2 + half;
            int ar = (w << 5) | l31;
            uint32_t aoff = ((uint32_t)ar << 7) | ((uint32_t)(ch ^ (ar & 7)) << 4);
            bf16x8 ahi = *(const bf16x8*)(smem + AHI + aoff);
            bf16x8 alo = *(const bf16x8*)(smem + ALO + aoff);
            uint32_t sw = (uint32_t)(ch ^ (l31 & 7)) << 4;
            bf16x8 b0 = *(const bf16x8*)(smem + BOFF + ((uint32_t)l31 << 7) + sw);
            bf16x8 b1 = *(const bf16x8*)(smem + BOFF + ((uint32_t)(32 + l31) << 7) + sw);
            bf16x8 b2 = *(const bf16x8*)(smem + BOFF + ((uint32_t)(64 + l31) << 7) + sw);
            accR = __builtin_amdgcn_mfma_f32_32x32x16_bf16(ahi, b0, accR, 0, 0, 0);
            accZ = __builtin_amdgcn_mfma_f32_32x32x16_bf16(ahi, b1, accZ, 0, 0, 0);
            accN = __builtin_amdgcn_mfma_f32_32x32x16_bf16(ahi, b2, accN, 0, 0, 0);
            accR = __builtin_amdgcn_mfma_f32_32x32x16_bf16(alo, b0, accR, 0, 0, 0);
            accZ = __builtin_amdgcn_mfma_f32_32x32x16_bf16(alo, b1, accZ, 0, 0, 0);
            accN = __builtin_amdgcn_mfma_f32_32x32x16_bf16(alo, b2, accN, 0, 0, 0);
        }
        __syncthreads();
    }

    // epilogue: gates + state update; stash out-partials in LDS (reuse A region)
    float* prod = (float*)(smem + AHI);  // [128][32][2]
    int jcg = Jbase + l31;
    const float4* pkp = (const float4*)(pk + (size_t)jcg * 12);
    float4 p0 = pkp[0], p1 = pkp[1], p2 = pkp[2];
    // p0={wxr0,wxr1,wxz0,wxz1} p1={wxn0,wxn1,bhr,bhz} p2={bhn,wo0,wo1,-}
    #pragma unroll
    for (int reg = 0; reg < 16; reg++) {
        int row = (reg & 3) + 8 * (reg >> 2) + 4 * half;
        int iloc = (w << 5) + row;
        size_t i = (size_t)Mbase + iloc;
        const float* gi = gi2 + (i * 512 + jcg) * 3;
        float g0 = gi[0], g1 = gi[1], g2v = gi[2];
        float x0 = xs[iloc * 2], x1 = xs[iloc * 2 + 1];
        float r = sigm_f(g0 + p0.x * x0 + p0.y * x1 + accR[reg] + p1.z);
        float u = sigm_f(g1 + p0.z * x0 + p0.w * x1 + accZ[reg] + p1.w);
        float nn = tanh_f(g2v + p1.x * x0 + p1.y * x1 + r * (accN[reg] + p2.x));
        float hold = (float)hhi_in[i * 512 + jcg] + (float)hlo_in[i * 512 + jcg];
        float hn = (1.f - u) * nn + u * hold;
        __bf16 hb = (__bf16)hn;
        hhi_out[i * 512 + jcg] = hb;
        hlo_out[i * 512 + jcg] = (__bf16)(hn - (float)hb);
        ((float2*)prod)[iloc * 32 + l31] = make_float2(hn * p2.y, hn * p2.z);
    }
    __syncthreads();
    {
        int i = tid >> 1, d = tid & 1;
        float s = 0.f;
        #pragma unroll
        for (int jj = 0; jj < 32; jj++) {
            int jc = (jj + i) & 31;   // skew to avoid bank conflicts
            s += prod[(i * 32 + jc) * 2 + d];
        }
        partial[((size_t)(Mbase + i) * 2 + d) * 16 + by] = s;
    }
}

// ---------------- K3: final output out_11 ----------------
__global__ __launch_bounds__(256) void k3_final(
    const float* __restrict__ partial, const float* __restrict__ b_out,
    float* __restrict__ dout)
{
    int gid = blockIdx.x * 256 + threadIdx.x;
    if (gid < 8192) {
        int i = gid >> 1, d = gid & 1;
        const float4* p = (const float4*)(partial + ((size_t)i * 2 + d) * 16);
        float4 a = p[0], b = p[1], c = p[2], e = p[3];
        float v = b_out[d] + a.x + a.y + a.z + a.w + b.x + b.y + b.z + b.w
                           + c.x + c.y + c.z + c.w + e.x + e.y + e.z + e.w;
        dout[((size_t)i * 12 + 11) * 2 + d] = v;
    }
}

extern "C" void kernel_launch(void* const* d_in, const int* in_sizes, int n_in,
                              void* d_out, int out_size, void* d_ws, size_t ws_size,
                              hipStream_t stream)
{
    const float* z     = (const float*)d_in[0];
    const float* x     = (const float*)d_in[1];
    const float* x0    = (const float*)d_in[2];
    const float* W_ia  = (const float*)d_in[3];
    const float* b_ia  = (const float*)d_in[4];
    const float* W_h0  = (const float*)d_in[5];
    const float* b_h0  = (const float*)d_in[6];
    const float* W_ih  = (const float*)d_in[7];
    const float* b_ih  = (const float*)d_in[8];
    const float* W_hh  = (const float*)d_in[9];
    const float* b_hh  = (const float*)d_in[10];
    const float* W_out = (const float*)d_in[11];
    const float* b_out = (const float*)d_in[12];
    float* dout = (float*)d_out;

    char* ws = (char*)d_ws;
    __bf16* hhi[2]; __bf16* hlo[2];
    hhi[0] = (__bf16*)(ws + 0);
    hlo[0] = (__bf16*)(ws + 4194304);
    hhi[1] = (__bf16*)(ws + 8388608);
    hlo[1] = (__bf16*)(ws + 12582912);
    float*  gi2    = (float*)(ws + 16777216);    // 4096*512*3 fp32
    __bf16* zx_hi  = (__bf16*)(ws + 41943040);
    __bf16* zx_lo  = (__bf16*)(ws + 44040192);
    __bf16* wcat   = (__bf16*)(ws + 46137344);   // 2048*256
    __bf16* whh_b  = (__bf16*)(ws + 47185920);   // 1536*512
    float*  pk     = (float*)(ws + 48758784);    // 512*12
    float*  xbuf   = (float*)(ws + 48783360);    // 4096*2
    float*  partial= (float*)(ws + 48816128);    // 4096*2*16

    k0_prep<<<2048, 256, 0, stream>>>(z, x, x0, W_ia, b_ia, W_ih, W_hh, W_h0,
                                      W_out, b_hh, zx_hi, zx_lo, wcat, whh_b, pk, xbuf);
    k1_precompute<<<dim3(32, 32), 256, 0, stream>>>(zx_hi, zx_lo, wcat, b_h0, b_ih,
                                                    hhi[0], hlo[0], gi2);
    for (int t = 0; t < 12; t++) {
        int ib = t & 1, ob = (t + 1) & 1;
        k2_step<<<dim3(32, 16), 256, 0, stream>>>(t, hhi[ib], hlo[ib], hhi[ob], hlo[ob],
                                                  whh_b, gi2, pk, xbuf, partial, dout, b_out);
    }
    k3_final<<<32, 256, 0, stream>>>(partial, b_out, dout);
}